// Round 16
// baseline (305.885 us; speedup 1.0000x reference)
//
#include <hip/hip_runtime.h>
#include <math.h>

#define SLOPE 0.2f
#define LOG2E 1.4426950408889634f

// --------------------------- fused gemm + histogram ----------------------
// gemm: z[node][o] = sum_k h[node][k]*W[o][k]. Block = 64 nodes x 32 chans
// (blockIdx&1 selects channel half), 256 threads, 2x4 register tile.
// W^T staged in LDS [128][36] with XOR swizzle (store 2-way, read 0-way).
// hist: 2 edges/thread into the blockIdx&7 XCD-private counter copy;
// fire-and-forget atomics. Copy mapping = (edge/512)&7 — the scatter
// kernel MUST use the same mapping.
__global__ __launch_bounds__(256, 8) void gemm_hist_kernel(const float* __restrict__ h,
                                                           const float* __restrict__ W,
                                                           float* __restrict__ z,
                                                           const int* __restrict__ dst,
                                                           int* __restrict__ cnt8,
                                                           int n, int ne) {
    // ---- histogram part (before any early return) ----
    int* __restrict__ cnt = cnt8 + (size_t)(blockIdx.x & 7) * n;
    int ei = blockIdx.x * 256 + threadIdx.x;
    int base = ei * 2;
    if (base + 1 < ne) {
        int2 d = *(const int2*)(dst + base);
        atomicAdd(&cnt[d.x], 1);
        atomicAdd(&cnt[d.y], 1);
    } else if (base < ne) {
        atomicAdd(&cnt[dst[base]], 1);
    }

    // ---- gemm part ----
    __shared__ float ws[128][36];     // 18.4 KB, W^T (swizzled cols)
    int t = threadIdx.x;
    int nblk = blockIdx.x >> 1;
    int ch0  = (blockIdx.x & 1) << 5;
    const float4* __restrict__ W4 = reinterpret_cast<const float4*>(W);
#pragma unroll
    for (int j = 0; j < 4; j++) {
        int idx = t + j * 256;            // 0..1023
        int o  = idx >> 5;                // 0..31 (local channel)
        int kq = idx & 31;                // float4 col index
        float4 w = W4[(size_t)(ch0 + o) * 32 + kq];
        int k = kq << 2;
        int col = o ^ ((kq & 7) << 2);    // XOR swizzle on og bits
        ws[k + 0][col] = w.x; ws[k + 1][col] = w.y;
        ws[k + 2][col] = w.z; ws[k + 3][col] = w.w;
    }
    __syncthreads();

    int ng = t >> 3, og = t & 7;
    int n0 = nblk * 64 + ng * 2;
    if (n0 >= n) return;                  // n even: rows n0, n0+1 both valid
    const float* __restrict__ hp = h + (size_t)n0 * 128;

    float acc[2][4] = {};
#pragma unroll 4
    for (int k = 0; k < 128; k += 4) {
        int m = (k >> 2) & 7;
        int colb = (og ^ m) << 2;
        float4 hv[2], wv[4];
#pragma unroll
        for (int i = 0; i < 2; i++) hv[i] = *(const float4*)(hp + i * 128 + k);
#pragma unroll
        for (int kk = 0; kk < 4; kk++) wv[kk] = *(const float4*)&ws[k + kk][colb];
#pragma unroll
        for (int i = 0; i < 2; i++) {
            acc[i][0] += hv[i].x * wv[0].x + hv[i].y * wv[1].x + hv[i].z * wv[2].x + hv[i].w * wv[3].x;
            acc[i][1] += hv[i].x * wv[0].y + hv[i].y * wv[1].y + hv[i].z * wv[2].y + hv[i].w * wv[3].y;
            acc[i][2] += hv[i].x * wv[0].z + hv[i].y * wv[1].z + hv[i].z * wv[2].z + hv[i].w * wv[3].z;
            acc[i][3] += hv[i].x * wv[0].w + hv[i].y * wv[1].w + hv[i].z * wv[2].w + hv[i].w * wv[3].w;
        }
    }
#pragma unroll
    for (int i = 0; i < 2; i++) {
        *(float4*)&z[(size_t)(n0 + i) * 64 + ch0 + og * 4] =
            make_float4(acc[i][0], acc[i][1], acc[i][2], acc[i][3]);
    }
}

// ---------------------- scan over 8-copy histogram ------------------------
// scan1: per-node total = sum of 8 copies; block-local exclusive prefix.
__global__ __launch_bounds__(256) void scan1(const int* __restrict__ cnt8,
                                             int* __restrict__ starts,
                                             int* __restrict__ bsums, int n) {
    __shared__ int ls[256];
    int tbase = blockIdx.x * 4096 + threadIdx.x * 16;
    int tot[16];
#pragma unroll
    for (int k = 0; k < 16; k++) tot[k] = 0;
    if (tbase + 15 < n) {
#pragma unroll
        for (int c = 0; c < 8; c++) {
            const int* cp = cnt8 + (size_t)c * n + tbase;
#pragma unroll
            for (int q = 0; q < 4; q++) {
                int4 v = *(const int4*)(cp + q * 4);
                tot[q * 4 + 0] += v.x; tot[q * 4 + 1] += v.y;
                tot[q * 4 + 2] += v.z; tot[q * 4 + 3] += v.w;
            }
        }
    } else {
        for (int k = 0; k < 16; k++) {
            int idx = tbase + k;
            if (idx < n)
                for (int c = 0; c < 8; c++) tot[k] += cnt8[(size_t)c * n + idx];
        }
    }
    int s = 0;
#pragma unroll
    for (int k = 0; k < 16; k++) s += tot[k];
    ls[threadIdx.x] = s;
    __syncthreads();
    for (int off = 1; off < 256; off <<= 1) {
        int t = threadIdx.x >= off ? ls[threadIdx.x - off] : 0;
        __syncthreads();
        ls[threadIdx.x] += t;
        __syncthreads();
    }
    int run = ls[threadIdx.x] - s;
    if (threadIdx.x == 255) bsums[blockIdx.x] = ls[255];
#pragma unroll
    for (int k = 0; k < 16; k++) {
        int idx = tbase + k;
        if (idx < n) starts[idx] = run;
        run += tot[k];
    }
}

__global__ void scan2(int* __restrict__ bsums, int nb, int* __restrict__ starts,
                      int n, int ne) {
    if (threadIdx.x == 0) {
        int run = 0;
        for (int b = 0; b < nb; b++) { int t = bsums[b]; bsums[b] = run; run += t; }
        starts[n] = ne;
    }
}

// scan3: finalize starts; convert cnt8 in place into per-copy cursors.
__global__ __launch_bounds__(256) void scan3(int* __restrict__ starts,
                                             const int* __restrict__ bsums,
                                             int* __restrict__ cnt8, int n) {
    int i = blockIdx.x * 256 + threadIdx.x;
    if (i >= n) return;
    int base = starts[i] + bsums[i >> 12];
    starts[i] = base;
#pragma unroll
    for (int c = 0; c < 8; c++) {
        size_t off = (size_t)c * n + i;
        int t = cnt8[off];
        cnt8[off] = base;
        base += t;
    }
}

// ------------- scatter src into CSR via XCD-private cursors --------------
// IDENTICAL edge<->block mapping to gemm_hist's histogram: 2 edges/thread,
// 512 edges/block, copy = blockIdx&7. Per-copy cursor usage then exactly
// matches per-copy counts.
__global__ __launch_bounds__(256) void scatter2_kernel(const int* __restrict__ src,
                                                       const int* __restrict__ dst,
                                                       int* __restrict__ cnt8,
                                                       int* __restrict__ csr_src,
                                                       int n, int ne) {
    int* __restrict__ cur = cnt8 + (size_t)(blockIdx.x & 7) * n;
    int ei = blockIdx.x * 256 + threadIdx.x;
    int base = ei * 2;
    if (base + 1 < ne) {
        int2 s = *(const int2*)(src + base);
        int2 d = *(const int2*)(dst + base);
        int p0 = atomicAdd(&cur[d.x], 1); csr_src[p0] = s.x;
        int p1 = atomicAdd(&cur[d.y], 1); csr_src[p1] = s.y;
    } else if (base < ne) {
        int p = atomicAdd(&cur[dst[base]], 1);
        csr_src[p] = src[base];
    }
}

// ------------- fused: dot + online softmax + aggregation + elu -----------
// One wave per node. lane = (g,q): g = edge slot (0..3), q = channel quad.
// exp2-domain online softmax with wave-uniform fast path (no max growth ->
// no rescale). One dwordx4 gather per lane fetches 4 edge rows per iter.
__global__ __launch_bounds__(256) void fused_node(const float4* __restrict__ z4,
                                                  const int* __restrict__ starts,
                                                  const int* __restrict__ csr_src,
                                                  float4* __restrict__ out4, int n) {
    int node = blockIdx.x * 4 + (threadIdx.x >> 6);
    if (node >= n) return;
    int lane = threadIdx.x & 63;
    int g = lane >> 4;
    int q = lane & 15;
    int rs = starts[node], re = starts[node + 1];
    float4 zd = z4[(size_t)node * 16 + q];

    float m2 = -1e30f, denom = 0.f;
    float4 acc = make_float4(0.f, 0.f, 0.f, 0.f);

    for (int c = rs; c < re; c += 64) {
        int j = c + lane;
        int sv = j < re ? csr_src[j] : 0;
        int cn = min(64, re - c);
        int idx = g;
        bool val = idx < cn;
        int s = __shfl(sv, val ? idx : 0);
        float4 v = z4[(size_t)s * 16 + q];
        for (int k = 0; k < cn; k += 4) {
            int idx_n = k + 4 + g;
            bool val_n = idx_n < cn;
            int s_n = __shfl(sv, val_n ? idx_n : 0);
            float4 vn = z4[(size_t)s_n * 16 + q];
            float p = v.x * zd.x + v.y * zd.y + v.z * zd.z + v.w * zd.w;
#pragma unroll
            for (int msk = 1; msk < 16; msk <<= 1) p += __shfl_xor(p, msk);
            float e = p > 0.f ? p : SLOPE * p;
            float e2 = e * LOG2E;
            e2 = val ? e2 : -2e30f;
            if (__any(e2 > m2)) {                 // max grew somewhere: rescale
                float mnew = fmaxf(m2, e2);
                float sc = exp2f(m2 - mnew);      // ==0 on first edge
                float ex = exp2f(e2 - mnew);      // ==0 for invalid slots
                denom = fmaf(denom, sc, ex);
                acc.x = fmaf(acc.x, sc, ex * v.x);
                acc.y = fmaf(acc.y, sc, ex * v.y);
                acc.z = fmaf(acc.z, sc, ex * v.z);
                acc.w = fmaf(acc.w, sc, ex * v.w);
                m2 = mnew;
            } else {                              // fast path: no rescale
                float ex = exp2f(e2 - m2);
                denom += ex;
                acc.x = fmaf(ex, v.x, acc.x);
                acc.y = fmaf(ex, v.y, acc.y);
                acc.z = fmaf(ex, v.z, acc.z);
                acc.w = fmaf(ex, v.w, acc.w);
            }
            v = vn; val = val_n;
        }
    }
    // merge the 4 group states (same q across groups)
#pragma unroll
    for (int msk = 16; msk < 64; msk <<= 1) {
        float mo  = __shfl_xor(m2, msk);
        float dno = __shfl_xor(denom, msk);
        float ax = __shfl_xor(acc.x, msk);
        float ay = __shfl_xor(acc.y, msk);
        float az = __shfl_xor(acc.z, msk);
        float aw = __shfl_xor(acc.w, msk);
        float mnew = fmaxf(m2, mo);
        float ss = exp2f(m2 - mnew), so = exp2f(mo - mnew);
        denom = fmaf(denom, ss, dno * so);
        acc.x = fmaf(acc.x, ss, ax * so);
        acc.y = fmaf(acc.y, ss, ay * so);
        acc.z = fmaf(acc.z, ss, az * so);
        acc.w = fmaf(acc.w, ss, aw * so);
        m2 = mnew;
    }
    if (lane < 16) {
        float inv = denom > 0.f ? 1.f / denom : 0.f;
        float4 r; float x;
        x = acc.x * inv; r.x = x > 0.f ? x : __expf(x) - 1.f;
        x = acc.y * inv; r.y = x > 0.f ? x : __expf(x) - 1.f;
        x = acc.z * inv; r.z = x > 0.f ? x : __expf(x) - 1.f;
        x = acc.w * inv; r.w = x > 0.f ? x : __expf(x) - 1.f;
        out4[(size_t)node * 16 + q] = r;
    }
}

// -------------------------------------------------------------- launch ----
extern "C" void kernel_launch(void* const* d_in, const int* in_sizes, int n_in,
                              void* d_out, int out_size, void* d_ws, size_t ws_size,
                              hipStream_t stream) {
    const float* h   = (const float*)d_in[0];
    const float* W   = (const float*)d_in[1];
    const int*   src = (const int*)d_in[2];
    const int*   dst = (const int*)d_in[3];
    int n  = in_sizes[0] / 128;   // 100000
    int ne = in_sizes[2];         // 1600000

    // 16B-aligned layout: z | cnt8 | csr_src | starts | bsums
    float* z       = (float*)d_ws;                    // n*64 floats (25.6 MB)
    int*   cnt8    = (int*)(z + (size_t)n * 64);      // 8n ints (3.2 MB)
    int*   csr_src = cnt8 + (size_t)8 * n;            // ne ints (6.4 MB)
    int*   starts  = csr_src + ne;                    // n+1 ints
    int*   bsums   = starts + ((n + 5) & ~3);         // 32 ints (aligned)

    int nb_gemm = ((n + 63) / 64) * 2;                // 3126
    int nb_edge = (ne / 2 + 255) / 256;               // 3125 (= hist mapping)
    int nb_scan = (n + 4095) / 4096;                  // 25

    hipMemsetAsync(cnt8, 0, (size_t)8 * n * sizeof(int), stream);
    gemm_hist_kernel<<<nb_gemm, 256, 0, stream>>>(h, W, z, dst, cnt8, n, ne);
    scan1<<<nb_scan, 256, 0, stream>>>(cnt8, starts, bsums, n);
    scan2<<<1, 64, 0, stream>>>(bsums, nb_scan, starts, n, ne);
    scan3<<<(n + 255) / 256, 256, 0, stream>>>(starts, bsums, cnt8, n);
    scatter2_kernel<<<nb_edge, 256, 0, stream>>>(src, dst, cnt8, csr_src, n, ne);
    fused_node<<<(n + 3) / 4, 256, 0, stream>>>((const float4*)z, starts, csr_src,
                                                (float4*)d_out, n);
}

// Round 17
// 203.927 us; speedup vs baseline: 1.5000x; 1.5000x over previous
//
#include <hip/hip_runtime.h>
#include <math.h>

#define SLOPE 0.2f
#define LOG2E 1.4426950408889634f

// --------------------------- fused gemm + histogram ----------------------
// gemm: z[node][o] = sum_k h[node][k]*W[o][k]. Block = 64 nodes x 32 chans
// (blockIdx&1 selects channel half), 256 threads, 2x4 register tile.
// W^T staged in LDS [128][36] with XOR swizzle (store 2-way, read 0-way).
// hist: 2 edges/thread, shared cnt, rank = atomic return (proven r14).
__global__ __launch_bounds__(256, 8) void gemm_hist_kernel(const float* __restrict__ h,
                                                           const float* __restrict__ W,
                                                           float* __restrict__ z,
                                                           const int* __restrict__ dst,
                                                           int* __restrict__ cnt,
                                                           int* __restrict__ rank,
                                                           int n, int ne) {
    // ---- histogram part (before any early return) ----
    int ei = blockIdx.x * 256 + threadIdx.x;
    int base = ei * 2;
    if (base + 1 < ne) {
        int2 d = *(const int2*)(dst + base);
        int2 r;
        r.x = atomicAdd(&cnt[d.x], 1);
        r.y = atomicAdd(&cnt[d.y], 1);
        *(int2*)(rank + base) = r;
    } else if (base < ne) {
        rank[base] = atomicAdd(&cnt[dst[base]], 1);
    }

    // ---- gemm part ----
    __shared__ float ws[128][36];     // 18.4 KB, W^T (swizzled cols)
    int t = threadIdx.x;
    int nblk = blockIdx.x >> 1;
    int ch0  = (blockIdx.x & 1) << 5;
    const float4* __restrict__ W4 = reinterpret_cast<const float4*>(W);
#pragma unroll
    for (int j = 0; j < 4; j++) {
        int idx = t + j * 256;            // 0..1023
        int o  = idx >> 5;                // 0..31 (local channel)
        int kq = idx & 31;                // float4 col index
        float4 w = W4[(size_t)(ch0 + o) * 32 + kq];
        int k = kq << 2;
        int col = o ^ ((kq & 7) << 2);    // XOR swizzle on og bits
        ws[k + 0][col] = w.x; ws[k + 1][col] = w.y;
        ws[k + 2][col] = w.z; ws[k + 3][col] = w.w;
    }
    __syncthreads();

    int ng = t >> 3, og = t & 7;
    int n0 = nblk * 64 + ng * 2;
    if (n0 >= n) return;                  // n even: rows n0, n0+1 both valid
    const float* __restrict__ hp = h + (size_t)n0 * 128;

    float acc[2][4] = {};
#pragma unroll 4
    for (int k = 0; k < 128; k += 4) {
        int m = (k >> 2) & 7;
        int colb = (og ^ m) << 2;
        float4 hv[2], wv[4];
#pragma unroll
        for (int i = 0; i < 2; i++) hv[i] = *(const float4*)(hp + i * 128 + k);
#pragma unroll
        for (int kk = 0; kk < 4; kk++) wv[kk] = *(const float4*)&ws[k + kk][colb];
#pragma unroll
        for (int i = 0; i < 2; i++) {
            acc[i][0] += hv[i].x * wv[0].x + hv[i].y * wv[1].x + hv[i].z * wv[2].x + hv[i].w * wv[3].x;
            acc[i][1] += hv[i].x * wv[0].y + hv[i].y * wv[1].y + hv[i].z * wv[2].y + hv[i].w * wv[3].y;
            acc[i][2] += hv[i].x * wv[0].z + hv[i].y * wv[1].z + hv[i].z * wv[2].z + hv[i].w * wv[3].z;
            acc[i][3] += hv[i].x * wv[0].w + hv[i].y * wv[1].w + hv[i].z * wv[2].w + hv[i].w * wv[3].w;
        }
    }
#pragma unroll
    for (int i = 0; i < 2; i++) {
        *(float4*)&z[(size_t)(n0 + i) * 64 + ch0 + og * 4] =
            make_float4(acc[i][0], acc[i][1], acc[i][2], acc[i][3]);
    }
}

// ------------------------------------------------- scan (4096/block) -----
__global__ __launch_bounds__(256) void scan1(const int* __restrict__ cnt,
                                             int* __restrict__ starts,
                                             int* __restrict__ bsums, int n) {
    __shared__ int ls[256];
    int tbase = blockIdx.x * 4096 + threadIdx.x * 16;
    int v[16];
    int s = 0;
#pragma unroll
    for (int k = 0; k < 16; k++) {
        int idx = tbase + k;
        int c = idx < n ? cnt[idx] : 0;
        v[k] = c; s += c;
    }
    ls[threadIdx.x] = s;
    __syncthreads();
    for (int off = 1; off < 256; off <<= 1) {
        int t = threadIdx.x >= off ? ls[threadIdx.x - off] : 0;
        __syncthreads();
        ls[threadIdx.x] += t;
        __syncthreads();
    }
    int run = ls[threadIdx.x] - s;
    if (threadIdx.x == 255) bsums[blockIdx.x] = ls[255];
#pragma unroll
    for (int k = 0; k < 16; k++) {
        int idx = tbase + k;
        if (idx < n) starts[idx] = run;
        run += v[k];
    }
}

__global__ void scan2(int* __restrict__ bsums, int nb, int* __restrict__ starts,
                      int n, int ne) {
    if (threadIdx.x == 0) {
        int run = 0;
        for (int b = 0; b < nb; b++) { int t = bsums[b]; bsums[b] = run; run += t; }
        starts[n] = ne;
    }
}

__global__ __launch_bounds__(256) void scan3(int* __restrict__ starts,
                                             const int* __restrict__ bsums, int n) {
    int i = blockIdx.x * 256 + threadIdx.x;
    if (i < n) starts[i] += bsums[i >> 12];
}

// --------------- scatter src into CSR (rank-based, 8 edges/thread) -------
__global__ __launch_bounds__(256) void scatter8_kernel(const int* __restrict__ src,
                                                       const int* __restrict__ dst,
                                                       const int* __restrict__ starts,
                                                       const int* __restrict__ rank,
                                                       int* __restrict__ csr_src, int ne) {
    int i = blockIdx.x * 256 + threadIdx.x;
    int base = i * 8;
    if (base + 7 < ne) {
        int4 s0 = *(const int4*)(src + base),  s1 = *(const int4*)(src + base + 4);
        int4 d0 = *(const int4*)(dst + base),  d1 = *(const int4*)(dst + base + 4);
        int4 r0 = *(const int4*)(rank + base), r1 = *(const int4*)(rank + base + 4);
        csr_src[starts[d0.x] + r0.x] = s0.x;
        csr_src[starts[d0.y] + r0.y] = s0.y;
        csr_src[starts[d0.z] + r0.z] = s0.z;
        csr_src[starts[d0.w] + r0.w] = s0.w;
        csr_src[starts[d1.x] + r1.x] = s1.x;
        csr_src[starts[d1.y] + r1.y] = s1.y;
        csr_src[starts[d1.z] + r1.z] = s1.z;
        csr_src[starts[d1.w] + r1.w] = s1.w;
    } else {
        for (int r = base; r < ne; r++)
            csr_src[starts[dst[r]] + rank[r]] = src[r];
    }
}

// ------------- fused: dot + online softmax + aggregation + elu -----------
// One wave per node. lane = (g,q): g = edge slot (0..3), q = channel quad.
// 2-deep gather pipeline (v0 reducing, v1 ready, v2 in flight) to cover
// L2/L3 gather latency. exp2-domain online softmax, wave-uniform fast path.
__global__ __launch_bounds__(256) void fused_node(const float4* __restrict__ z4,
                                                  const int* __restrict__ starts,
                                                  const int* __restrict__ csr_src,
                                                  float4* __restrict__ out4, int n) {
    int node = blockIdx.x * 4 + (threadIdx.x >> 6);
    if (node >= n) return;
    int lane = threadIdx.x & 63;
    int g = lane >> 4;
    int q = lane & 15;
    int rs = starts[node], re = starts[node + 1];
    float4 zd = z4[(size_t)node * 16 + q];

    float m2 = -1e30f, denom = 0.f;
    float4 acc = make_float4(0.f, 0.f, 0.f, 0.f);

    for (int c = rs; c < re; c += 64) {
        int j = c + lane;
        int sv = j < re ? csr_src[j] : 0;
        int cn = min(64, re - c);
        // 2-deep prologue (clamped indices -> always-safe loads)
        bool val0 = g < cn;
        int  s0 = __shfl(sv, val0 ? g : 0);
        float4 v0 = z4[(size_t)s0 * 16 + q];
        bool val1 = 4 + g < cn;
        int  s1 = __shfl(sv, val1 ? 4 + g : 0);
        float4 v1 = z4[(size_t)s1 * 16 + q];
        for (int k = 0; k < cn; k += 4) {
            int idx2 = k + 8 + g;
            bool val2 = idx2 < cn;
            int  s2 = __shfl(sv, val2 ? idx2 : 0);
            float4 v2 = z4[(size_t)s2 * 16 + q];
            float p = v0.x * zd.x + v0.y * zd.y + v0.z * zd.z + v0.w * zd.w;
#pragma unroll
            for (int msk = 1; msk < 16; msk <<= 1) p += __shfl_xor(p, msk);
            float e = p > 0.f ? p : SLOPE * p;
            float e2 = e * LOG2E;
            e2 = val0 ? e2 : -2e30f;
            if (__any(e2 > m2)) {                 // max grew somewhere: rescale
                float mnew = fmaxf(m2, e2);
                float sc = exp2f(m2 - mnew);      // ==0 on first edge
                float ex = exp2f(e2 - mnew);      // ==0 for invalid slots
                denom = fmaf(denom, sc, ex);
                acc.x = fmaf(acc.x, sc, ex * v0.x);
                acc.y = fmaf(acc.y, sc, ex * v0.y);
                acc.z = fmaf(acc.z, sc, ex * v0.z);
                acc.w = fmaf(acc.w, sc, ex * v0.w);
                m2 = mnew;
            } else {                              // fast path: no rescale
                float ex = exp2f(e2 - m2);
                denom += ex;
                acc.x = fmaf(ex, v0.x, acc.x);
                acc.y = fmaf(ex, v0.y, acc.y);
                acc.z = fmaf(ex, v0.z, acc.z);
                acc.w = fmaf(ex, v0.w, acc.w);
            }
            v0 = v1; val0 = val1;
            v1 = v2; val1 = val2;
        }
    }
    // merge the 4 group states (same q across groups)
#pragma unroll
    for (int msk = 16; msk < 64; msk <<= 1) {
        float mo  = __shfl_xor(m2, msk);
        float dno = __shfl_xor(denom, msk);
        float ax = __shfl_xor(acc.x, msk);
        float ay = __shfl_xor(acc.y, msk);
        float az = __shfl_xor(acc.z, msk);
        float aw = __shfl_xor(acc.w, msk);
        float mnew = fmaxf(m2, mo);
        float ss = exp2f(m2 - mnew), so = exp2f(mo - mnew);
        denom = fmaf(denom, ss, dno * so);
        acc.x = fmaf(acc.x, ss, ax * so);
        acc.y = fmaf(acc.y, ss, ay * so);
        acc.z = fmaf(acc.z, ss, az * so);
        acc.w = fmaf(acc.w, ss, aw * so);
        m2 = mnew;
    }
    if (lane < 16) {
        float inv = denom > 0.f ? 1.f / denom : 0.f;
        float4 r; float x;
        x = acc.x * inv; r.x = x > 0.f ? x : __expf(x) - 1.f;
        x = acc.y * inv; r.y = x > 0.f ? x : __expf(x) - 1.f;
        x = acc.z * inv; r.z = x > 0.f ? x : __expf(x) - 1.f;
        x = acc.w * inv; r.w = x > 0.f ? x : __expf(x) - 1.f;
        out4[(size_t)node * 16 + q] = r;
    }
}

// -------------------------------------------------------------- launch ----
extern "C" void kernel_launch(void* const* d_in, const int* in_sizes, int n_in,
                              void* d_out, int out_size, void* d_ws, size_t ws_size,
                              hipStream_t stream) {
    const float* h   = (const float*)d_in[0];
    const float* W   = (const float*)d_in[1];
    const int*   src = (const int*)d_in[2];
    const int*   dst = (const int*)d_in[3];
    int n  = in_sizes[0] / 128;   // 100000
    int ne = in_sizes[2];         // 1600000

    // 16B-aligned layout: z | rank | csr_src | cnt | starts | bsums
    float* z       = (float*)d_ws;                    // n*64 floats (25.6 MB)
    int*   rank    = (int*)(z + (size_t)n * 64);      // ne ints (6.4 MB)
    int*   csr_src = rank + ne;                       // ne ints (6.4 MB)
    int*   cnt     = csr_src + ne;                    // n ints
    int*   starts  = cnt + n;                         // n+1 ints
    int*   bsums   = starts + ((n + 5) & ~3);         // 32 ints

    int nb_gemm = ((n + 63) / 64) * 2;                // 3126 (covers ne/512)
    int nb_scan = (n + 4095) / 4096;                  // 25

    hipMemsetAsync(cnt, 0, (size_t)n * sizeof(int), stream);
    gemm_hist_kernel<<<nb_gemm, 256, 0, stream>>>(h, W, z, dst, cnt, rank, n, ne);
    scan1<<<nb_scan, 256, 0, stream>>>(cnt, starts, bsums, n);
    scan2<<<1, 64, 0, stream>>>(bsums, nb_scan, starts, n, ne);
    scan3<<<(n + 255) / 256, 256, 0, stream>>>(starts, bsums, n);
    scatter8_kernel<<<(ne / 8 + 255) / 256, 256, 0, stream>>>(src, dst, starts,
                                                              rank, csr_src, ne);
    fused_node<<<(n + 3) / 4, 256, 0, stream>>>((const float4*)z, starts, csr_src,
                                                (float4*)d_out, n);
}